// Round 5
// baseline (2406.222 us; speedup 1.0000x reference)
//
#include <hip/hip_runtime.h>
#include <math.h>

// CrossModalAttentionFusion: B=262144, D=32, 3 tokens, 4 heads. f32 in/out.
// R4 post-mortem: spill-bound (332MB fetch/288MB write vs ~104/33 ideal,
// VGPR capped at 128). R5: (a) launch_bounds(256,1) + lean transients so
// f[3][32]+acc[3][32] stay in VGPRs; (b) heavy/light compaction so waves
// aren't dragged through the 13600-op path for count<=1 samples.

#define NEGV (-1e9f)
#define LN_EPS 1e-5f
typedef unsigned int  u32;
typedef unsigned char u8;

// ---------- mask-encoding detection (byte-packed vs int32), as R4 ----------
__global__ void cmaf_detect(const u32* __restrict__ mwords, u32* __restrict__ flag,
                            int nwords)
{
    int i = blockIdx.x * 256 + threadIdx.x;
    bool bad = false;
    #pragma unroll
    for (int k = 0; k < 4; ++k) {
        int idx = i * 4 + k;
        if (idx < nwords) { u32 w = mwords[idx]; bad |= (w > 1u); }
    }
    unsigned long long any = __ballot(bad);
    if ((threadIdx.x & 63) == 0 && any) atomicOr(flag, 1u);
}

// ---------- classify: build heavy (count>=2) / light lists ----------
// entry = sample_idx | m0<<24 | m1<<25 | m2<<26
__global__ void cmaf_classify(const void* __restrict__ masks_raw,
                              const u32* __restrict__ flagp,
                              u32* __restrict__ cnt,        // [0]=heavy,[1]=light
                              u32* __restrict__ heavyList,
                              u32* __restrict__ lightList, int B)
{
    int i = blockIdx.x * 256 + threadIdx.x;
    if (i >= B) return;
    bool m0, m1, m2;
    if (*flagp) {
        const u8* mb = (const u8*)masks_raw;
        m0 = mb[3*i+0] != 0; m1 = mb[3*i+1] != 0; m2 = mb[3*i+2] != 0;
    } else {
        const int* mi = (const int*)masks_raw;
        m0 = mi[3*i+0] != 0; m1 = mi[3*i+1] != 0; m2 = mi[3*i+2] != 0;
    }
    int count = (int)m0 + (int)m1 + (int)m2;
    u32 e = (u32)i | ((u32)m0 << 24) | ((u32)m1 << 25) | ((u32)m2 << 26);
    if (count >= 2) heavyList[atomicAdd(&cnt[0], 1u)] = e;
    else            lightList[atomicAdd(&cnt[1], 1u)] = e;
}

// ---------- heavy path (count>=2), lean-register version ----------
__device__ __forceinline__ void heavy_path(int b, bool m0, bool m1, bool m2,
    const float* __restrict__ metric, const float* __restrict__ logx,
    const float* __restrict__ trace,
    const float* __restrict__ Win, const float* __restrict__ bin,
    const float* __restrict__ Wout, const float* __restrict__ bout,
    const float* __restrict__ mw, const float* __restrict__ gam,
    const float* __restrict__ bet, float* __restrict__ out)
{
    float f[3][32];
    {
        const float4* p0 = reinterpret_cast<const float4*>(metric + (size_t)b*32);
        const float4* p1 = reinterpret_cast<const float4*>(logx   + (size_t)b*32);
        const float4* p2 = reinterpret_cast<const float4*>(trace  + (size_t)b*32);
        #pragma unroll
        for (int i = 0; i < 8; ++i) {
            float4 a = p0[i];
            f[0][4*i+0]=a.x; f[0][4*i+1]=a.y; f[0][4*i+2]=a.z; f[0][4*i+3]=a.w;
            float4 c = p1[i];
            f[1][4*i+0]=c.x; f[1][4*i+1]=c.y; f[1][4*i+2]=c.z; f[1][4*i+3]=c.w;
            float4 d = p2[i];
            f[2][4*i+0]=d.x; f[2][4*i+1]=d.y; f[2][4*i+2]=d.z; f[2][4*i+3]=d.w;
        }
    }

    float w0, w1, w2;
    {
        float l0 = m0 ? mw[0] : NEGV;
        float l1 = m1 ? mw[1] : NEGV;
        float l2 = m2 ? mw[2] : NEGV;
        float mx = fmaxf(l0, fmaxf(l1, l2));
        float e0 = __expf(l0 - mx), e1 = __expf(l1 - mx), e2 = __expf(l2 - mx);
        float inv = 1.f / (e0 + e1 + e2);
        w0 = e0*inv; w1 = e1*inv; w2 = e2*inv;
    }

    float acc[3][32];
    #pragma unroll
    for (int s = 0; s < 3; ++s)
        #pragma unroll
        for (int o = 0; o < 32; ++o) acc[s][o] = 0.f;

    const float scale = 0.35355339059327373f;  // 1/sqrt(8)

    #pragma unroll 1
    for (int h = 0; h < 4; ++h) {
        float kk[3][8], vv[3][8];
        #pragma unroll
        for (int s = 0; s < 3; ++s) {
            #pragma unroll
            for (int d = 0; d < 8; ++d) {
                const int r = h*8 + d;                 // wave-uniform -> s_load
                float ak = bin[32 + r];
                float av = bin[64 + r];
                const float* wkr = Win + (size_t)(32 + r)*32;
                const float* wvr = Win + (size_t)(64 + r)*32;
                #pragma unroll
                for (int j = 0; j < 32; ++j) {
                    float x = f[s][j];
                    ak = fmaf(x, wkr[j], ak);
                    av = fmaf(x, wvr[j], av);
                }
                kk[s][d] = ak; vv[s][d] = av;
            }
        }
        #pragma unroll
        for (int sq = 0; sq < 3; ++sq) {
            // q-dot streamed: qd element consumed immediately into scores
            float s0 = 0.f, s1 = 0.f, s2 = 0.f;
            #pragma unroll
            for (int d = 0; d < 8; ++d) {
                const int r = h*8 + d;
                float aq = bin[r];
                const float* wqr = Win + (size_t)r*32;
                #pragma unroll
                for (int j = 0; j < 32; ++j) aq = fmaf(f[sq][j], wqr[j], aq);
                s0 = fmaf(aq, kk[0][d], s0);
                s1 = fmaf(aq, kk[1][d], s1);
                s2 = fmaf(aq, kk[2][d], s2);
            }
            s0 = m0 ? s0*scale : NEGV;
            s1 = m1 ? s1*scale : NEGV;
            s2 = m2 ? s2*scale : NEGV;
            float mx = fmaxf(s0, fmaxf(s1, s2));
            float e0 = __expf(s0 - mx), e1 = __expf(s1 - mx), e2 = __expf(s2 - mx);
            float inv = 1.f / (e0 + e1 + e2);
            e0 *= inv; e1 *= inv; e2 *= inv;
            // ctx element streamed into the out-proj fold (no ctx array)
            #pragma unroll
            for (int d = 0; d < 8; ++d) {
                float c = e0*vv[0][d] + e1*vv[1][d] + e2*vv[2][d];
                const float* wc = Wout + h*8 + d;      // column, stride 32; uniform
                #pragma unroll
                for (int o = 0; o < 32; ++o)
                    acc[sq][o] = fmaf(c, wc[(size_t)o*32], acc[sq][o]);
            }
        }
    }

    // epilogue: weighted residual + LayerNorm + weighted sum
    float fused[32];
    #pragma unroll
    for (int o = 0; o < 32; ++o) fused[o] = 0.f;

    #pragma unroll
    for (int s = 0; s < 3; ++s) {
        const float ws = (s == 0) ? w0 : (s == 1) ? w1 : w2;
        float row[32];
        float mu = 0.f;
        #pragma unroll
        for (int o = 0; o < 32; ++o) {
            float a = acc[s][o] + bout[o];
            row[o] = fmaf(a, ws, f[s][o]);
            mu += row[o];
        }
        mu *= (1.f/32.f);
        float var = 0.f;
        #pragma unroll
        for (int o = 0; o < 32; ++o) { float d = row[o] - mu; var = fmaf(d, d, var); }
        var *= (1.f/32.f);
        const float rs = rsqrtf(var + LN_EPS);
        #pragma unroll
        for (int o = 0; o < 32; ++o) {
            float y = (row[o] - mu) * rs * gam[o] + bet[o];
            fused[o] = fmaf(ws, y, fused[o]);
        }
    }

    float4* po = reinterpret_cast<float4*>(out + (size_t)b*32);
    #pragma unroll
    for (int i = 0; i < 8; ++i) {
        float4 r;
        r.x = fused[4*i+0]; r.y = fused[4*i+1]; r.z = fused[4*i+2]; r.w = fused[4*i+3];
        po[i] = r;
    }
}

__device__ __forceinline__ void light_path(int b, bool m0, bool m1, bool m2,
    const float* __restrict__ metric, const float* __restrict__ logx,
    const float* __restrict__ trace, float* __restrict__ out)
{
    // count<=1: output = the single available row (or zeros)
    const float* src = m0 ? metric : (m1 ? logx : (m2 ? trace : nullptr));
    float4* po = reinterpret_cast<float4*>(out + (size_t)b*32);
    if (src) {
        const float4* ps = reinterpret_cast<const float4*>(src + (size_t)b*32);
        #pragma unroll
        for (int k = 0; k < 8; ++k) po[k] = ps[k];
    } else {
        float4 z; z.x = z.y = z.z = z.w = 0.f;
        #pragma unroll
        for (int k = 0; k < 8; ++k) po[k] = z;
    }
}

__global__ __launch_bounds__(256, 1) void cmaf_heavy(
    const u32* __restrict__ list, const u32* __restrict__ cnt,
    const float* __restrict__ metric, const float* __restrict__ logx,
    const float* __restrict__ trace,
    const float* __restrict__ Win, const float* __restrict__ bin,
    const float* __restrict__ Wout, const float* __restrict__ bout,
    const float* __restrict__ mw, const float* __restrict__ gam,
    const float* __restrict__ bet, float* __restrict__ out)
{
    u32 n = cnt[0];
    u32 i = blockIdx.x * 256 + threadIdx.x;
    if (i >= n) return;
    u32 e = list[i];
    heavy_path((int)(e & 0xFFFFFFu), (e >> 24) & 1u, (e >> 25) & 1u, (e >> 26) & 1u,
               metric, logx, trace, Win, bin, Wout, bout, mw, gam, bet, out);
}

__global__ __launch_bounds__(256) void cmaf_light(
    const u32* __restrict__ list, const u32* __restrict__ cnt,
    const float* __restrict__ metric, const float* __restrict__ logx,
    const float* __restrict__ trace, float* __restrict__ out)
{
    u32 n = cnt[1];
    u32 i = blockIdx.x * 256 + threadIdx.x;
    if (i >= n) return;
    u32 e = list[i];
    light_path((int)(e & 0xFFFFFFu), (e >> 24) & 1u, (e >> 25) & 1u, (e >> 26) & 1u,
               metric, logx, trace, out);
}

// fallback if d_ws is too small for the lists (keeps R4 behavior)
__global__ __launch_bounds__(256, 1) void cmaf_mono(
    const void* __restrict__ masks_raw, const u32* __restrict__ flagp,
    const float* __restrict__ metric, const float* __restrict__ logx,
    const float* __restrict__ trace,
    const float* __restrict__ Win, const float* __restrict__ bin,
    const float* __restrict__ Wout, const float* __restrict__ bout,
    const float* __restrict__ mw, const float* __restrict__ gam,
    const float* __restrict__ bet, float* __restrict__ out, int B)
{
    int b = blockIdx.x * 256 + threadIdx.x;
    if (b >= B) return;
    bool m0, m1, m2;
    if (*flagp) {
        const u8* mb = (const u8*)masks_raw;
        m0 = mb[3*b+0] != 0; m1 = mb[3*b+1] != 0; m2 = mb[3*b+2] != 0;
    } else {
        const int* mi = (const int*)masks_raw;
        m0 = mi[3*b+0] != 0; m1 = mi[3*b+1] != 0; m2 = mi[3*b+2] != 0;
    }
    if ((int)m0 + (int)m1 + (int)m2 <= 1)
        light_path(b, m0, m1, m2, metric, logx, trace, out);
    else
        heavy_path(b, m0, m1, m2, metric, logx, trace, Win, bin, Wout, bout,
                   mw, gam, bet, out);
}

extern "C" void kernel_launch(void* const* d_in, const int* in_sizes, int n_in,
                              void* d_out, int out_size, void* d_ws, size_t ws_size,
                              hipStream_t stream) {
    const float* metric = (const float*)d_in[0];
    const float* logx   = (const float*)d_in[1];
    const float* trace  = (const float*)d_in[2];
    const void*  masks  = d_in[3];
    const float* Win    = (const float*)d_in[4];
    const float* bin    = (const float*)d_in[5];
    const float* Wout   = (const float*)d_in[6];
    const float* bout   = (const float*)d_in[7];
    const float* mw     = (const float*)d_in[8];
    const float* gam    = (const float*)d_in[9];
    const float* bet    = (const float*)d_in[10];
    float* out = (float*)d_out;

    const int B = in_sizes[0] / 32;         // 262144
    const int grid = (B + 255) / 256;

    u32* ws        = (u32*)d_ws;
    u32* flag      = ws;                    // [0]
    u32* cnt       = ws + 1;                // [1],[2]
    u32* heavyList = ws + 4;                // [4, 4+B)
    u32* lightList = ws + 4 + B;            // [4+B, 4+2B)
    const size_t need = (size_t)(4 + 2*(size_t)B) * 4;

    // detect mask encoding: scan 3B/4 words (valid size under both encodings)
    const int nwords = (3 * B) / 4;
    const int dgrid = (nwords / 4 + 255) / 256;

    hipMemsetAsync(d_ws, 0, 16, stream);
    hipLaunchKernelGGL(cmaf_detect, dim3(dgrid), dim3(256), 0, stream,
                       (const u32*)masks, flag, nwords);

    if (ws_size >= need) {
        hipLaunchKernelGGL(cmaf_classify, dim3(grid), dim3(256), 0, stream,
                           masks, flag, cnt, heavyList, lightList, B);
        hipLaunchKernelGGL(cmaf_heavy, dim3(grid), dim3(256), 0, stream,
                           heavyList, cnt, metric, logx, trace,
                           Win, bin, Wout, bout, mw, gam, bet, out);
        hipLaunchKernelGGL(cmaf_light, dim3(grid), dim3(256), 0, stream,
                           lightList, cnt, metric, logx, trace, out);
    } else {
        hipLaunchKernelGGL(cmaf_mono, dim3(grid), dim3(256), 0, stream,
                           masks, flag, metric, logx, trace,
                           Win, bin, Wout, bout, mw, gam, bet, out, B);
    }
}

// Round 6
// 473.428 us; speedup vs baseline: 5.0825x; 5.0825x over previous
//
#include <hip/hip_runtime.h>
#include <math.h>

// CrossModalAttentionFusion: B=262144, D=32, 3 tokens, 4 heads. f32 in/out.
// R5 post-mortem: cmaf_classify was atomic-serialization-bound (262144
// atomicAdds on 2 addresses = 2020us, VALUBusy 0.01%). R6: wave-aggregated
// compaction -- one atomicAdd per wave per class (8192 total), in-wave
// offsets from ballot popcount. Heavy/light/detect paths unchanged.

#define NEGV (-1e9f)
#define LN_EPS 1e-5f
typedef unsigned int  u32;
typedef unsigned char u8;
typedef unsigned long long u64;

// ---------- mask-encoding detection (byte-packed vs int32) ----------
__global__ void cmaf_detect(const u32* __restrict__ mwords, u32* __restrict__ flag,
                            int nwords)
{
    int i = blockIdx.x * 256 + threadIdx.x;
    bool bad = false;
    #pragma unroll
    for (int k = 0; k < 4; ++k) {
        int idx = i * 4 + k;
        if (idx < nwords) { u32 w = mwords[idx]; bad |= (w > 1u); }
    }
    unsigned long long any = __ballot(bad);
    if ((threadIdx.x & 63) == 0 && any) atomicOr(flag, 1u);
}

// ---------- classify: wave-aggregated stream compaction ----------
// entry = sample_idx | m0<<24 | m1<<25 | m2<<26. B is a multiple of 256,
// so every lane of every wave is active (ballot math is exact).
__global__ __launch_bounds__(256) void cmaf_classify(
    const void* __restrict__ masks_raw,
    const u32* __restrict__ flagp,
    u32* __restrict__ cnt,        // [0]=heavy,[1]=light
    u32* __restrict__ heavyList,
    u32* __restrict__ lightList, int B)
{
    int i = blockIdx.x * 256 + threadIdx.x;
    if (i >= B) return;
    bool m0, m1, m2;
    if (*flagp) {
        const u8* mb = (const u8*)masks_raw;
        m0 = mb[3*i+0] != 0; m1 = mb[3*i+1] != 0; m2 = mb[3*i+2] != 0;
    } else {
        const int* mi = (const int*)masks_raw;
        m0 = mi[3*i+0] != 0; m1 = mi[3*i+1] != 0; m2 = mi[3*i+2] != 0;
    }
    const bool heavy = ((int)m0 + (int)m1 + (int)m2) >= 2;
    const u32 e = (u32)i | ((u32)m0 << 24) | ((u32)m1 << 25) | ((u32)m2 << 26);

    const int lane = threadIdx.x & 63;
    const u64 below = (lane == 63) ? ~0ull >> 1 : ((1ull << lane) - 1ull);

    const u64 hb = __ballot(heavy);
    const u64 lb = ~hb;                       // all lanes active -> complement

    u32 hbase = 0, lbase = 0;
    if (lane == 0) {
        hbase = atomicAdd(&cnt[0], (u32)__popcll(hb));
        lbase = atomicAdd(&cnt[1], (u32)__popcll(lb));
    }
    hbase = __shfl(hbase, 0, 64);
    lbase = __shfl(lbase, 0, 64);

    if (heavy) heavyList[hbase + __popcll(hb & below)] = e;
    else       lightList[lbase + __popcll(lb & below)] = e;
}

// ---------- heavy path (count>=2), lean-register version ----------
__device__ __forceinline__ void heavy_path(int b, bool m0, bool m1, bool m2,
    const float* __restrict__ metric, const float* __restrict__ logx,
    const float* __restrict__ trace,
    const float* __restrict__ Win, const float* __restrict__ bin,
    const float* __restrict__ Wout, const float* __restrict__ bout,
    const float* __restrict__ mw, const float* __restrict__ gam,
    const float* __restrict__ bet, float* __restrict__ out)
{
    float f[3][32];
    {
        const float4* p0 = reinterpret_cast<const float4*>(metric + (size_t)b*32);
        const float4* p1 = reinterpret_cast<const float4*>(logx   + (size_t)b*32);
        const float4* p2 = reinterpret_cast<const float4*>(trace  + (size_t)b*32);
        #pragma unroll
        for (int i = 0; i < 8; ++i) {
            float4 a = p0[i];
            f[0][4*i+0]=a.x; f[0][4*i+1]=a.y; f[0][4*i+2]=a.z; f[0][4*i+3]=a.w;
            float4 c = p1[i];
            f[1][4*i+0]=c.x; f[1][4*i+1]=c.y; f[1][4*i+2]=c.z; f[1][4*i+3]=c.w;
            float4 d = p2[i];
            f[2][4*i+0]=d.x; f[2][4*i+1]=d.y; f[2][4*i+2]=d.z; f[2][4*i+3]=d.w;
        }
    }

    float w0, w1, w2;
    {
        float l0 = m0 ? mw[0] : NEGV;
        float l1 = m1 ? mw[1] : NEGV;
        float l2 = m2 ? mw[2] : NEGV;
        float mx = fmaxf(l0, fmaxf(l1, l2));
        float e0 = __expf(l0 - mx), e1 = __expf(l1 - mx), e2 = __expf(l2 - mx);
        float inv = 1.f / (e0 + e1 + e2);
        w0 = e0*inv; w1 = e1*inv; w2 = e2*inv;
    }

    float acc[3][32];
    #pragma unroll
    for (int s = 0; s < 3; ++s)
        #pragma unroll
        for (int o = 0; o < 32; ++o) acc[s][o] = 0.f;

    const float scale = 0.35355339059327373f;  // 1/sqrt(8)

    #pragma unroll 1
    for (int h = 0; h < 4; ++h) {
        float kk[3][8], vv[3][8];
        #pragma unroll
        for (int s = 0; s < 3; ++s) {
            #pragma unroll
            for (int d = 0; d < 8; ++d) {
                const int r = h*8 + d;                 // wave-uniform -> s_load
                float ak = bin[32 + r];
                float av = bin[64 + r];
                const float* wkr = Win + (size_t)(32 + r)*32;
                const float* wvr = Win + (size_t)(64 + r)*32;
                #pragma unroll
                for (int j = 0; j < 32; ++j) {
                    float x = f[s][j];
                    ak = fmaf(x, wkr[j], ak);
                    av = fmaf(x, wvr[j], av);
                }
                kk[s][d] = ak; vv[s][d] = av;
            }
        }
        #pragma unroll
        for (int sq = 0; sq < 3; ++sq) {
            float s0 = 0.f, s1 = 0.f, s2 = 0.f;
            #pragma unroll
            for (int d = 0; d < 8; ++d) {
                const int r = h*8 + d;
                float aq = bin[r];
                const float* wqr = Win + (size_t)r*32;
                #pragma unroll
                for (int j = 0; j < 32; ++j) aq = fmaf(f[sq][j], wqr[j], aq);
                s0 = fmaf(aq, kk[0][d], s0);
                s1 = fmaf(aq, kk[1][d], s1);
                s2 = fmaf(aq, kk[2][d], s2);
            }
            s0 = m0 ? s0*scale : NEGV;
            s1 = m1 ? s1*scale : NEGV;
            s2 = m2 ? s2*scale : NEGV;
            float mx = fmaxf(s0, fmaxf(s1, s2));
            float e0 = __expf(s0 - mx), e1 = __expf(s1 - mx), e2 = __expf(s2 - mx);
            float inv = 1.f / (e0 + e1 + e2);
            e0 *= inv; e1 *= inv; e2 *= inv;
            #pragma unroll
            for (int d = 0; d < 8; ++d) {
                float c = e0*vv[0][d] + e1*vv[1][d] + e2*vv[2][d];
                const float* wc = Wout + h*8 + d;      // column, stride 32; uniform
                #pragma unroll
                for (int o = 0; o < 32; ++o)
                    acc[sq][o] = fmaf(c, wc[(size_t)o*32], acc[sq][o]);
            }
        }
    }

    float fused[32];
    #pragma unroll
    for (int o = 0; o < 32; ++o) fused[o] = 0.f;

    #pragma unroll
    for (int s = 0; s < 3; ++s) {
        const float ws = (s == 0) ? w0 : (s == 1) ? w1 : w2;
        float row[32];
        float mu = 0.f;
        #pragma unroll
        for (int o = 0; o < 32; ++o) {
            float a = acc[s][o] + bout[o];
            row[o] = fmaf(a, ws, f[s][o]);
            mu += row[o];
        }
        mu *= (1.f/32.f);
        float var = 0.f;
        #pragma unroll
        for (int o = 0; o < 32; ++o) { float d = row[o] - mu; var = fmaf(d, d, var); }
        var *= (1.f/32.f);
        const float rs = rsqrtf(var + LN_EPS);
        #pragma unroll
        for (int o = 0; o < 32; ++o) {
            float y = (row[o] - mu) * rs * gam[o] + bet[o];
            fused[o] = fmaf(ws, y, fused[o]);
        }
    }

    float4* po = reinterpret_cast<float4*>(out + (size_t)b*32);
    #pragma unroll
    for (int i = 0; i < 8; ++i) {
        float4 r;
        r.x = fused[4*i+0]; r.y = fused[4*i+1]; r.z = fused[4*i+2]; r.w = fused[4*i+3];
        po[i] = r;
    }
}

__device__ __forceinline__ void light_path(int b, bool m0, bool m1, bool m2,
    const float* __restrict__ metric, const float* __restrict__ logx,
    const float* __restrict__ trace, float* __restrict__ out)
{
    const float* src = m0 ? metric : (m1 ? logx : (m2 ? trace : nullptr));
    float4* po = reinterpret_cast<float4*>(out + (size_t)b*32);
    if (src) {
        const float4* ps = reinterpret_cast<const float4*>(src + (size_t)b*32);
        #pragma unroll
        for (int k = 0; k < 8; ++k) po[k] = ps[k];
    } else {
        float4 z; z.x = z.y = z.z = z.w = 0.f;
        #pragma unroll
        for (int k = 0; k < 8; ++k) po[k] = z;
    }
}

__global__ __launch_bounds__(256, 1) void cmaf_heavy(
    const u32* __restrict__ list, const u32* __restrict__ cnt,
    const float* __restrict__ metric, const float* __restrict__ logx,
    const float* __restrict__ trace,
    const float* __restrict__ Win, const float* __restrict__ bin,
    const float* __restrict__ Wout, const float* __restrict__ bout,
    const float* __restrict__ mw, const float* __restrict__ gam,
    const float* __restrict__ bet, float* __restrict__ out)
{
    u32 n = cnt[0];
    u32 i = blockIdx.x * 256 + threadIdx.x;
    if (i >= n) return;
    u32 e = list[i];
    heavy_path((int)(e & 0xFFFFFFu), (e >> 24) & 1u, (e >> 25) & 1u, (e >> 26) & 1u,
               metric, logx, trace, Win, bin, Wout, bout, mw, gam, bet, out);
}

__global__ __launch_bounds__(256) void cmaf_light(
    const u32* __restrict__ list, const u32* __restrict__ cnt,
    const float* __restrict__ metric, const float* __restrict__ logx,
    const float* __restrict__ trace, float* __restrict__ out)
{
    u32 n = cnt[1];
    u32 i = blockIdx.x * 256 + threadIdx.x;
    if (i >= n) return;
    u32 e = list[i];
    light_path((int)(e & 0xFFFFFFu), (e >> 24) & 1u, (e >> 25) & 1u, (e >> 26) & 1u,
               metric, logx, trace, out);
}

// fallback if d_ws is too small for the lists
__global__ __launch_bounds__(256, 1) void cmaf_mono(
    const void* __restrict__ masks_raw, const u32* __restrict__ flagp,
    const float* __restrict__ metric, const float* __restrict__ logx,
    const float* __restrict__ trace,
    const float* __restrict__ Win, const float* __restrict__ bin,
    const float* __restrict__ Wout, const float* __restrict__ bout,
    const float* __restrict__ mw, const float* __restrict__ gam,
    const float* __restrict__ bet, float* __restrict__ out, int B)
{
    int b = blockIdx.x * 256 + threadIdx.x;
    if (b >= B) return;
    bool m0, m1, m2;
    if (*flagp) {
        const u8* mb = (const u8*)masks_raw;
        m0 = mb[3*b+0] != 0; m1 = mb[3*b+1] != 0; m2 = mb[3*b+2] != 0;
    } else {
        const int* mi = (const int*)masks_raw;
        m0 = mi[3*b+0] != 0; m1 = mi[3*b+1] != 0; m2 = mi[3*b+2] != 0;
    }
    if ((int)m0 + (int)m1 + (int)m2 <= 1)
        light_path(b, m0, m1, m2, metric, logx, trace, out);
    else
        heavy_path(b, m0, m1, m2, metric, logx, trace, Win, bin, Wout, bout,
                   mw, gam, bet, out);
}

extern "C" void kernel_launch(void* const* d_in, const int* in_sizes, int n_in,
                              void* d_out, int out_size, void* d_ws, size_t ws_size,
                              hipStream_t stream) {
    const float* metric = (const float*)d_in[0];
    const float* logx   = (const float*)d_in[1];
    const float* trace  = (const float*)d_in[2];
    const void*  masks  = d_in[3];
    const float* Win    = (const float*)d_in[4];
    const float* bin    = (const float*)d_in[5];
    const float* Wout   = (const float*)d_in[6];
    const float* bout   = (const float*)d_in[7];
    const float* mw     = (const float*)d_in[8];
    const float* gam    = (const float*)d_in[9];
    const float* bet    = (const float*)d_in[10];
    float* out = (float*)d_out;

    const int B = in_sizes[0] / 32;         // 262144
    const int grid = (B + 255) / 256;

    u32* ws        = (u32*)d_ws;
    u32* flag      = ws;                    // [0]
    u32* cnt       = ws + 1;                // [1],[2]
    u32* heavyList = ws + 4;                // [4, 4+B)
    u32* lightList = ws + 4 + B;            // [4+B, 4+2B)
    const size_t need = (size_t)(4 + 2*(size_t)B) * 4;

    const int nwords = (3 * B) / 4;
    const int dgrid = (nwords / 4 + 255) / 256;

    hipMemsetAsync(d_ws, 0, 16, stream);
    hipLaunchKernelGGL(cmaf_detect, dim3(dgrid), dim3(256), 0, stream,
                       (const u32*)masks, flag, nwords);

    if (ws_size >= need) {
        hipLaunchKernelGGL(cmaf_classify, dim3(grid), dim3(256), 0, stream,
                           masks, flag, cnt, heavyList, lightList, B);
        hipLaunchKernelGGL(cmaf_heavy, dim3(grid), dim3(256), 0, stream,
                           heavyList, cnt, metric, logx, trace,
                           Win, bin, Wout, bout, mw, gam, bet, out);
        hipLaunchKernelGGL(cmaf_light, dim3(grid), dim3(256), 0, stream,
                           lightList, cnt, metric, logx, trace, out);
    } else {
        hipLaunchKernelGGL(cmaf_mono, dim3(grid), dim3(256), 0, stream,
                           masks, flag, metric, logx, trace,
                           Win, bin, Wout, bout, mw, gam, bet, out, B);
    }
}